// Round 1
// baseline (861.783 us; speedup 1.0000x reference)
//
#include <hip/hip_runtime.h>

// out[b][d] = z[b][d] + a[d][labels_idx[b]] * labels_scale[b]
// B = 1048576, Z_DIM = 128, K = 512

// Pre-pass: transpose a (Z_DIM x K) -> aT (K x Z_DIM) in workspace.
// Tiny (256 KB), one-time per launch; uncoalesced reads negligible.
__global__ void A_76278619177037_transpose(const float* __restrict__ a,
                                           float* __restrict__ aT,
                                           int zdim, int K) {
    int idx = blockIdx.x * blockDim.x + threadIdx.x;  // over K * zdim
    if (idx < K * zdim) {
        int k = idx / zdim;
        int d = idx - k * zdim;
        aT[idx] = a[d * K + k];  // aT[k][d] = a[d][k]
    }
}

// Main: grid-stride, 2048 blocks x 256 threads.
// 8 rows per block-iteration, 32 lanes per row, float4 per lane (16B/lane).
// labels loaded per-row-group directly (same-address broadcast, L1 hit) —
// no LDS, no __syncthreads. z/out fully coalesced; aT row gather is a
// contiguous 512B L2 hit (aT = 256 KB, resident in every XCD L2).
__global__ void __launch_bounds__(256) A_76278619177037_kernel(
    const float4* __restrict__ z4,
    const float4* __restrict__ aT4,
    const int* __restrict__ labels_idx,
    const float* __restrict__ labels_scale,
    float4* __restrict__ out4,
    int B) {
    const int r = threadIdx.x >> 5;        // row slot within block: 0..7
    const int c = threadIdx.x & 31;        // float4 column: 0..31
    const int rowStride = gridDim.x << 3;  // 8 rows per block per iteration

    for (int row = (blockIdx.x << 3) + r; row < B; row += rowStride) {
        const int   k = labels_idx[row];     // 32-lane broadcast load
        const float s = labels_scale[row];   // 32-lane broadcast load

        const long long zoff = (long long)row * 32 + c;
        const float4 zv = z4[zoff];
        const float4 av = aT4[((long long)k << 5) + c];

        float4 o;
        o.x = zv.x + av.x * s;
        o.y = zv.y + av.y * s;
        o.z = zv.z + av.z * s;
        o.w = zv.w + av.w * s;
        out4[zoff] = o;
    }
}

extern "C" void kernel_launch(void* const* d_in, const int* in_sizes, int n_in,
                              void* d_out, int out_size, void* d_ws, size_t ws_size,
                              hipStream_t stream) {
    const float* z = (const float*)d_in[0];            // (B, 128)
    const float* a = (const float*)d_in[1];            // (128, 512)
    const int* labels_idx = (const int*)d_in[2];       // (B,)
    const float* labels_scale = (const float*)d_in[3]; // (B,)
    float* out = (float*)d_out;                        // (B, 128)

    const int B = in_sizes[3];
    const int zdim = 128;
    const int K = in_sizes[1] / zdim;  // 512

    float* aT = (float*)d_ws;  // K * zdim floats = 256 KB

    // Transpose a -> aT
    int n_t = K * zdim;
    A_76278619177037_transpose<<<(n_t + 255) / 256, 256, 0, stream>>>(a, aT, zdim, K);

    // Fused gather + axpy, grid-strided: 2048 blocks = 8 blocks/CU on 256 CUs,
    // 32 waves/CU (full occupancy at this VGPR count). 64 iterations/block.
    int total_chunks = (B + 7) / 8;
    int blocks = total_chunks < 2048 ? total_chunks : 2048;
    A_76278619177037_kernel<<<blocks, 256, 0, stream>>>(
        (const float4*)z, (const float4*)aT, labels_idx, labels_scale,
        (float4*)out, B);
}

// Round 2
// 830.136 us; speedup vs baseline: 1.0381x; 1.0381x over previous
//
#include <hip/hip_runtime.h>

// out[b][d] = z[b][d] + a[d][labels_idx[b]] * labels_scale[b]
// B = 1048576, Z_DIM = 128, K = 512

// Pre-pass: transpose a (Z_DIM x K) -> aT (K x Z_DIM) in workspace.
// Tiny (256 KB), one-time per launch; uncoalesced reads are negligible here.
__global__ void A_76278619177037_transpose(const float* __restrict__ a,
                                           float* __restrict__ aT,
                                           int zdim, int K) {
    int idx = blockIdx.x * blockDim.x + threadIdx.x;  // over K * zdim
    if (idx < K * zdim) {
        int k = idx / zdim;
        int d = idx - k * zdim;
        aT[idx] = a[d * K + k];  // aT[k][d] = a[d][k]
    }
}

// Main: 256 threads/block = 8 rows/block, 32 lanes per row, float4 per lane.
// z/out fully coalesced 16B/lane; aT row gather is contiguous 512B -> L2 hit.
// One chunk per block (131072 blocks): dense sweep preserves DRAM locality;
// LDS label staging keeps the broadcast loads off the critical load path.
// [R1 post-mortem: grid-stride 2048-block variant regressed 832->862 us.]
__global__ void __launch_bounds__(256) A_76278619177037_kernel(
    const float4* __restrict__ z4,
    const float4* __restrict__ aT4,
    const int* __restrict__ labels_idx,
    const float* __restrict__ labels_scale,
    float4* __restrict__ out4,
    int B) {
    __shared__ int s_k[8];
    __shared__ float s_s[8];

    int row0 = blockIdx.x * 8;
    if (threadIdx.x < 8) {
        int r = row0 + threadIdx.x;
        s_k[threadIdx.x] = (r < B) ? labels_idx[r] : 0;
        s_s[threadIdx.x] = (r < B) ? labels_scale[r] : 0.0f;
    }
    __syncthreads();

    int r = threadIdx.x >> 5;   // row within block: 0..7
    int c = threadIdx.x & 31;   // float4 column: 0..31 (128 floats/row)
    int row = row0 + r;
    if (row >= B) return;

    long long zoff = (long long)row * 32 + c;
    float4 zv = z4[zoff];
    float4 av = aT4[(long long)s_k[r] * 32 + c];
    float s = s_s[r];

    float4 o;
    o.x = zv.x + av.x * s;
    o.y = zv.y + av.y * s;
    o.z = zv.z + av.z * s;
    o.w = zv.w + av.w * s;
    out4[zoff] = o;
}

extern "C" void kernel_launch(void* const* d_in, const int* in_sizes, int n_in,
                              void* d_out, int out_size, void* d_ws, size_t ws_size,
                              hipStream_t stream) {
    const float* z = (const float*)d_in[0];            // (B, 128)
    const float* a = (const float*)d_in[1];            // (128, 512)
    const int* labels_idx = (const int*)d_in[2];       // (B,)
    const float* labels_scale = (const float*)d_in[3]; // (B,)
    float* out = (float*)d_out;                        // (B, 128)

    const int B = in_sizes[3];
    const int zdim = 128;
    const int K = in_sizes[1] / zdim;  // 512

    float* aT = (float*)d_ws;  // K * zdim floats = 256 KB

    // Transpose a -> aT
    int n_t = K * zdim;
    A_76278619177037_transpose<<<(n_t + 255) / 256, 256, 0, stream>>>(a, aT, zdim, K);

    // Fused gather + axpy
    int blocks = (B + 7) / 8;
    A_76278619177037_kernel<<<blocks, 256, 0, stream>>>(
        (const float4*)z, (const float4*)aT, labels_idx, labels_scale,
        (float4*)out, B);
}